// Round 6
// baseline (18067.252 us; speedup 1.0000x reference)
//
#include <hip/hip_runtime.h>

#define TT 128
#define INF 171

typedef _Float16 half8 __attribute__((ext_vector_type(8)));
typedef float floatx4 __attribute__((ext_vector_type(4)));
typedef unsigned short u16;

#define XBSZ 163840   // 8 btiles * 40 kc * 512
#define HSZ  131072   // 8 btiles * 32 kc * 512

__device__ __forceinline__ u16 f2h(float f){
  _Float16 h = (_Float16)f;
  return __builtin_bit_cast(u16, h);
}
__device__ __forceinline__ float sigm(float x){ return 1.f/(1.f+__expf(-x)); }
__device__ __forceinline__ float tanh_(float x){ return 1.f - 2.f/(__expf(2.f*x)+1.f); }

// scatter one fp16 value into a fragment-ordered activation buffer
// layout: [btile][kchunk(nch)][lane(64)][8] ; lane = ((k>>3)&3)*16 + (b&15), elem = k&7
__device__ __forceinline__ void scat(u16* buf, int nch, int b, int k, u16 v){
  buf[ (size_t)((((b>>4)*nch + (k>>5))*4 + ((k>>3)&3))*16 + (b&15))*8 + (k&7) ] = v;
}

// ---------------- weight prep (fragment-swizzled fp16) ----------------
__global__ __launch_bounds__(256) void prep_w1f(const float* __restrict__ Wih1,
    const float* __restrict__ Whh1, u16* __restrict__ Wf){
  int u = blockIdx.x*256 + threadIdx.x;          // exactly 655360 units
  int tile = u / 2560;
  int r = u - tile*2560;
  int kc = r >> 6, l = r & 63;
  int row = (tile>>6)*1024 + (tile&63)*16 + (l&15);
  int k0 = kc*32 + ((l>>4)<<3);
  half8 hv;
  #pragma unroll
  for (int e=0;e<8;e++){
    int k = k0+e;
    float w = 0.f;
    if (k < 171)       w = Wih1[(size_t)row*171 + k];
    else if (k < 1195) w = Whh1[(size_t)row*1024 + (k-171)];
    hv[e] = (_Float16)w;
  }
  *(half8*)&Wf[(size_t)(tile*40 + kc)*512 + (size_t)l*8] = hv;
}

__global__ __launch_bounds__(256) void prep_w23f(const float* __restrict__ Wih2,
    const float* __restrict__ Whh2, const float* __restrict__ Wih3,
    const float* __restrict__ Whh3, u16* __restrict__ W2f, u16* __restrict__ W3f){
  int u = blockIdx.x*256 + threadIdx.x;          // exactly 1048576 units
  int tile = u >> 12;
  int r = u & 4095;
  int kc = r >> 6, l = r & 63;
  int row = (tile>>6)*1024 + (tile&63)*16 + (l&15);
  int k0 = kc*32 + ((l>>4)<<3);
  half8 h2, h3;
  #pragma unroll
  for (int e=0;e<8;e++){
    int k = k0+e;
    size_t si = (size_t)row*1024 + (k & 1023);
    h2[e] = (_Float16)((k < 1024) ? Wih2[si] : Whh2[si]);
    h3[e] = (_Float16)((k < 1024) ? Wih3[si] : Whh3[si]);
  }
  size_t base = (size_t)(tile*64 + kc)*512 + (size_t)l*8;
  *(half8*)&W2f[base] = h2;
  *(half8*)&W3f[base] = h3;
}

__global__ __launch_bounds__(256) void prep_wdecf(const float* __restrict__ Wdec,
    u16* __restrict__ Wdf){
  int u = blockIdx.x*256 + threadIdx.x;          // exactly 22528 units
  int tile = u / 2048;
  int r = u & 2047;
  int kc = r >> 6, l = r & 63;
  int row = tile*16 + (l&15);
  int k0 = kc*32 + ((l>>4)<<3);
  half8 hv;
  #pragma unroll
  for (int e=0;e<8;e++){
    int k = k0+e;
    hv[e] = (_Float16)((row < 171) ? Wdec[(size_t)row*1024 + k] : 0.f);
  }
  *(half8*)&Wdf[(size_t)(tile*32 + kc)*512 + (size_t)l*8] = hv;
}

// biases + activation-buffer init (+ step-0 frame) + c init + barrier counters
__global__ __launch_bounds__(256) void prep_misc(
    const float* __restrict__ rseq, const int* __restrict__ gnp,
    const float* __restrict__ bih1, const float* __restrict__ bhh1,
    const float* __restrict__ bih2, const float* __restrict__ bhh2,
    const float* __restrict__ bih3, const float* __restrict__ bhh3,
    const float* __restrict__ bdec,
    u16* __restrict__ Xb1f, u16* __restrict__ Hf, float* __restrict__ cbuf,
    float* __restrict__ b1, float* __restrict__ b2, float* __restrict__ b3,
    float* __restrict__ bd, int* __restrict__ bar)
{
  size_t idx = (size_t)blockIdx.x*256 + threadIdx.x;
  if (idx < 327680){                       // Xb1f: 2 parities x [8][40][512]
    int q = (int)(idx / 163840);
    int rem = (int)(idx % 163840);
    int btile = rem / 20480;
    int r2 = rem % 20480;
    int kc = r2 >> 9, r3 = r2 & 511;
    int l = r3 >> 3, e = r3 & 7;
    int b = btile*16 + (l&15);
    int k = kc*32 + ((l>>4)<<3) + e;
    float v = 0.f;
    if (q==0 && k < 171 && *gnp > 0) v = rseq[(size_t)b*TT*INF + k];
    Xb1f[idx] = f2h(v);
    return;
  }
  idx -= 327680;
  if (idx < 786432){ Hf[idx] = 0; return; }        // H0/H1/H2 x 2 parities
  idx -= 786432;
  if (idx < 393216){ cbuf[idx] = 0.f; return; }    // c0,c1,c2
  idx -= 393216;
  if (idx < 12288){
    int which = (int)(idx >> 12), j = (int)(idx & 4095);
    float v = (which==0)? (bih1[j]+bhh1[j]) : (which==1)? (bih2[j]+bhh2[j]) : (bih3[j]+bhh3[j]);
    ((which==0)?b1:(which==1)?b2:b3)[j] = v;
    return;
  }
  idx -= 12288;
  if (idx < 176){ bd[idx] = (idx < 171) ? bdec[idx] : 0.f; return; }
  idx -= 176;
  if (idx < 512) bar[idx] = 0;
}

// ---------------- two-level grid barrier (device scope, cross-XCD safe) ------
// bar layout: c1[i] at bar[i*32] (8 counters, 128B apart), c0 at bar[256], gen at bar[288]
__device__ __forceinline__ void gridbar(int* __restrict__ bar, int bId, int* s_dead){
  __syncthreads();
  if (threadIdx.x == 0 && !(*s_dead)){
    int* c1 = &bar[(bId & 7) * 32];
    int* c0 = &bar[256];
    int* gen = &bar[288];
    int g = __hip_atomic_load(gen, __ATOMIC_RELAXED, __HIP_MEMORY_SCOPE_AGENT);
    bool release_done = false;
    int o1 = __hip_atomic_fetch_add(c1, 1, __ATOMIC_ACQ_REL, __HIP_MEMORY_SCOPE_AGENT);
    if (o1 == 31){
      int o0 = __hip_atomic_fetch_add(c0, 1, __ATOMIC_ACQ_REL, __HIP_MEMORY_SCOPE_AGENT);
      if (o0 == 7){
        #pragma unroll
        for (int i=0;i<8;i++)
          __hip_atomic_store(&bar[i*32], 0, __ATOMIC_RELAXED, __HIP_MEMORY_SCOPE_AGENT);
        __hip_atomic_store(c0, 0, __ATOMIC_RELAXED, __HIP_MEMORY_SCOPE_AGENT);
        __hip_atomic_store(gen, g+1, __ATOMIC_RELEASE, __HIP_MEMORY_SCOPE_AGENT);
        release_done = true;
      }
    }
    if (!release_done){
      long long t0 = clock64();
      while (__hip_atomic_load(gen, __ATOMIC_ACQUIRE, __HIP_MEMORY_SCOPE_AGENT) == g){
        __builtin_amdgcn_s_sleep(4);
        if (clock64() - t0 > 20000000LL){ *s_dead = 1; break; }  // ~8ms escape
      }
    }
    __threadfence();
  }
  __syncthreads();
}

// ---------------- LSTM phase: ping-pong register pipeline, full K ------------
// wave g = gate g, M=16 units (js), N=32 batch (nq), full K. No K-loop barriers.
template<int NCA, int NCB>
__device__ __forceinline__ void lstm_phase(
    const u16* __restrict__ Wf, const u16* XA, const u16* XB,
    const float* __restrict__ bias, float* __restrict__ cb,
    u16* hd0, int nch0, int koff0, u16* hd1, int nch1, int koff1,
    int js, int nq, int tid, int g, int l, float (*gb)[16][33])
{
  constexpr int NCH = NCA + NCB;
  constexpr int NG  = NCH/8;       // groups of 8 chunks
  constexpr int NGA = NCA/8;       // groups sourced from XA
  const int l15 = l & 15, lq = l >> 4;
  const u16* wp  = Wf + (size_t)(g*64 + js)*NCH*512 + (size_t)(l<<3);
  const u16* xa0 = XA + (size_t)(nq*2    )*NCA*512 + (size_t)(l<<3);
  const u16* xa1 = XA + (size_t)(nq*2 + 1)*NCA*512 + (size_t)(l<<3);
  const u16* xb0 = (NCB>0) ? XB + (size_t)(nq*2    )*NCB*512 + (size_t)(l<<3) : xa0;
  const u16* xb1 = (NCB>0) ? XB + (size_t)(nq*2 + 1)*NCB*512 + (size_t)(l<<3) : xa1;

  half8 W[2][8], X0[2][8], X1[2][8];
  {
    const u16* b0 = (0 < NGA) ? xa0 : xb0;
    const u16* b1 = (0 < NGA) ? xa1 : xb1;
    #pragma unroll
    for (int i=0;i<8;i++){
      W [0][i] = *(const half8*)(wp + (size_t)i*512);
      X0[0][i] = *(const half8*)(b0 + (size_t)i*512);
      X1[0][i] = *(const half8*)(b1 + (size_t)i*512);
    }
  }
  floatx4 a0{}, a1{};
  #pragma unroll 2
  for (int g8=0; g8<NG; g8++){
    const int cur = g8 & 1, nxt = cur ^ 1;
    if (g8+1 < NG){
      const int gn = g8+1;
      const u16* wn = wp + (size_t)gn*4096;
      const u16* b0 = (gn < NGA) ? xa0 + (size_t)gn*4096 : xb0 + (size_t)(gn-NGA)*4096;
      const u16* b1 = (gn < NGA) ? xa1 + (size_t)gn*4096 : xb1 + (size_t)(gn-NGA)*4096;
      #pragma unroll
      for (int i=0;i<8;i++){
        W [nxt][i] = *(const half8*)(wn + (size_t)i*512);
        X0[nxt][i] = *(const half8*)(b0 + (size_t)i*512);
        X1[nxt][i] = *(const half8*)(b1 + (size_t)i*512);
      }
    }
    #pragma unroll
    for (int i=0;i<8;i++){
      a0 = __builtin_amdgcn_mfma_f32_16x16x32_f16(W[cur][i], X0[cur][i], a0, 0,0,0);
      a1 = __builtin_amdgcn_mfma_f32_16x16x32_f16(W[cur][i], X1[cur][i], a1, 0,0,0);
    }
  }

  #pragma unroll
  for (int r=0;r<4;r++){
    gb[g][lq*4+r][l15]      = a0[r];
    gb[g][lq*4+r][16 + l15] = a1[r];
  }
  __syncthreads();

  #pragma unroll
  for (int rep=0; rep<2; rep++){
    int p = tid + rep*256;
    int uu = p >> 5, bq = p & 31;
    int j = js*16 + uu, bg = nq*32 + bq;
    float gi = gb[0][uu][bq] + bias[j];
    float gf = gb[1][uu][bq] + bias[1024 + j];
    float gg = gb[2][uu][bq] + bias[2048 + j];
    float go = gb[3][uu][bq] + bias[3072 + j];
    size_t ci = (size_t)j*128 + bg;
    float c = sigm(gf)*cb[ci] + sigm(gi)*tanh_(gg);
    cb[ci] = c;
    u16 hb = f2h(sigm(go)*tanh_(c));
    scat(hd0, nch0, bg, koff0 + j, hb);
    if (nch1) scat(hd1, nch1, bg, koff1 + j, hb);
  }
}

// ---------------- the persistent kernel: 256 blocks, 128 steps ----------------
// Regular launch: grid=256 blocks, each CU hosts >=1 block => all co-resident.
__global__ void __launch_bounds__(256,1) acro_persist(
    const u16* __restrict__ W1f, const u16* __restrict__ W2f,
    const u16* __restrict__ W3f, const u16* __restrict__ Wdf,
    u16* __restrict__ Xb1f, u16* __restrict__ Hf, float* __restrict__ cbuf,
    const float* __restrict__ b1, const float* __restrict__ b2,
    const float* __restrict__ b3, const float* __restrict__ bd,
    const float* __restrict__ rseq, float* __restrict__ out,
    const int* __restrict__ cnp, const int* __restrict__ gnp, int* __restrict__ bar)
{
  __shared__ float gb[4][16][33];
  __shared__ int s_dead;
  const int bId = (int)blockIdx.x;
  const int js = (bId & 7)*8 + ((bId >> 5) & 7);   // 4 nq-siblings share XCD class
  const int nq = (bId >> 3) & 3;
  const int tid = (int)threadIdx.x;
  const int g = tid >> 6, l = tid & 63;
  const int l15 = l & 15, lq = l >> 4;
  if (tid == 0) s_dead = 0;
  const int gn = *gnp;
  int P = *cnp + gn; if (P < 1) P = 1;

  u16* H0[2] = { Hf,          Hf + HSZ   };
  u16* H1[2] = { Hf + 2*HSZ,  Hf + 3*HSZ };
  u16* H2[2] = { Hf + 4*HSZ,  Hf + 5*HSZ };
  const u16* W23[2] = { W2f, W3f };
  const float* b23[2] = { b2, b3 };

  __syncthreads();
  for (int t=0; t<TT; t++){
    const int pr = t & 1, nx = pr ^ 1;
    // ---- L1: x = [frame | h0(t-1)] ----
    lstm_phase<40,0>(W1f, Xb1f + (size_t)pr*XBSZ, (const u16*)nullptr,
        b1, cbuf, H0[pr], 32, 0, Xb1f + (size_t)nx*XBSZ, 40, 171,
        js, nq, tid, g, l, gb);
    gridbar(bar, bId, &s_dead);
    // ---- L2, L3 ----
    #pragma unroll 1
    for (int ly=0; ly<2; ly++){
      const u16* xa = (ly==0) ? H0[pr] : H1[pr];
      const u16* xb = (ly==0) ? H1[nx] : H2[nx];
      u16* hd      = (ly==0) ? H1[pr] : H2[pr];
      lstm_phase<32,32>(W23[ly], xa, xb,
          b23[ly], cbuf + (size_t)(ly+1)*131072, hd, 32, 0, (u16*)nullptr, 0, 0,
          js, nq, tid, g, l, gb);
      gridbar(bar, bId, &s_dead);
    }
    // ---- dec: blocks 0..43 = (tile 0..10) x (dq 0..3); waves split K ----
    if (bId < 44){
      const int tile = bId >> 2, dq = bId & 3;
      const u16* wp = Wdf + (size_t)(tile*32 + g*8)*512 + (size_t)(l<<3);
      const u16* x0 = H2[pr] + (size_t)((dq*2    )*32 + g*8)*512 + (size_t)(l<<3);
      const u16* x1 = H2[pr] + (size_t)((dq*2 + 1)*32 + g*8)*512 + (size_t)(l<<3);
      floatx4 d0{}, d1{};
      #pragma unroll
      for (int i=0;i<8;i++){
        half8 wv = *(const half8*)(wp + (size_t)i*512);
        half8 a0 = *(const half8*)(x0 + (size_t)i*512);
        half8 a1 = *(const half8*)(x1 + (size_t)i*512);
        d0 = __builtin_amdgcn_mfma_f32_16x16x32_f16(wv, a0, d0, 0,0,0);
        d1 = __builtin_amdgcn_mfma_f32_16x16x32_f16(wv, a1, d1, 0,0,0);
      }
      #pragma unroll
      for (int r=0;r<4;r++){
        gb[g][lq*4+r][l15]      = d0[r];
        gb[g][lq*4+r][16 + l15] = d1[r];
      }
      __syncthreads();
      const int nf = (((t+1) % P) < gn) ? 1 : 0;
      #pragma unroll
      for (int rep=0; rep<2; rep++){
        int p = tid + rep*256;
        int uu = p >> 5, bq = p & 31;
        int o = tile*16 + uu, b = dq*32 + bq;
        if (o < 171){
          float v = gb[0][uu][bq] + gb[1][uu][bq] + gb[2][uu][bq] + gb[3][uu][bq] + bd[o];
          out[((size_t)b*TT + t)*INF + o] = v;
          if (t+1 < TT){
            float src = nf ? rseq[((size_t)b*TT + (t+1))*INF + o] : v;
            scat(Xb1f + (size_t)nx*XBSZ, 40, b, o, f2h(src));
          }
        }
      }
    }
    gridbar(bar, bId, &s_dead);
  }
}

// ---------------- host ----------------
extern "C" void kernel_launch(void* const* d_in, const int* in_sizes, int n_in,
                              void* d_out, int out_size, void* d_ws, size_t ws_size,
                              hipStream_t stream)
{
  const float* rseq = (const float*)d_in[0];
  const float* Wih1 = (const float*)d_in[1];
  const float* Whh1 = (const float*)d_in[2];
  const float* bih1 = (const float*)d_in[3];
  const float* bhh1 = (const float*)d_in[4];
  const float* Wih2 = (const float*)d_in[5];
  const float* Whh2 = (const float*)d_in[6];
  const float* bih2 = (const float*)d_in[7];
  const float* bhh2 = (const float*)d_in[8];
  const float* Wih3 = (const float*)d_in[9];
  const float* Whh3 = (const float*)d_in[10];
  const float* bih3 = (const float*)d_in[11];
  const float* bhh3 = (const float*)d_in[12];
  const float* Wdec = (const float*)d_in[13];
  const float* bdec = (const float*)d_in[14];
  const int* cn = (const int*)d_in[15];
  const int* gn = (const int*)d_in[16];
  float* out = (float*)d_out;

  char* p = (char*)d_ws;
  auto take = [&](size_t n){ void* r = (void*)p; p += (n + 255) & ~(size_t)255; return r; };
  u16* W1f  = (u16*)take(5242880UL*2);      // 256*40*512
  u16* W2f  = (u16*)take(8388608UL*2);      // 256*64*512
  u16* W3f  = (u16*)take(8388608UL*2);
  u16* Wdf  = (u16*)take(180224UL*2);       // 11*32*512
  u16* Xb1f = (u16*)take(327680UL*2);       // 2 parities x [8][40][512]
  u16* Hf   = (u16*)take(786432UL*2);       // 6 x [8][32][512]
  float* cbuf = (float*)take(393216UL*4);   // c0,c1,c2 [1024][128]
  float* b1 = (float*)take(4096*4);
  float* b2 = (float*)take(4096*4);
  float* b3 = (float*)take(4096*4);
  float* bd = (float*)take(176*4);
  int* bar  = (int*)take(512*4);
  if ((size_t)(p - (char*)d_ws) > ws_size) return;

  prep_w1f  <<<2560,256,0,stream>>>(Wih1, Whh1, W1f);
  prep_w23f <<<4096,256,0,stream>>>(Wih2, Whh2, Wih3, Whh3, W2f, W3f);
  prep_wdecf<<<88,  256,0,stream>>>(Wdec, Wdf);
  prep_misc <<<5939,256,0,stream>>>(rseq, gn, bih1,bhh1,bih2,bhh2,bih3,bhh3,bdec,
                                    Xb1f, Hf, cbuf, b1,b2,b3,bd, bar);

  acro_persist<<<256,256,0,stream>>>(W1f, W2f, W3f, Wdf, Xb1f, Hf, cbuf,
                                     b1, b2, b3, bd, rseq, out, cn, gn, bar);
}

// Round 7
// 8028.475 us; speedup vs baseline: 2.2504x; 2.2504x over previous
//
#include <hip/hip_runtime.h>

#define TT 128
#define INF 171

typedef _Float16 half8 __attribute__((ext_vector_type(8)));
typedef float floatx4 __attribute__((ext_vector_type(4)));
typedef unsigned short u16;

#define XBSZ 163840   // 8 btiles * 40 kc * 512
#define HSZ  131072   // 8 btiles * 32 kc * 512

__device__ __forceinline__ u16 f2h(float f){
  _Float16 h = (_Float16)f;
  return __builtin_bit_cast(u16, h);
}
__device__ __forceinline__ float sigm(float x){ return 1.f/(1.f+__expf(-x)); }
__device__ __forceinline__ float tanh_(float x){ return 1.f - 2.f/(__expf(2.f*x)+1.f); }

// scatter one fp16 value into a fragment-ordered activation buffer
// layout: [btile][kchunk(nch)][lane(64)][8] ; lane = ((k>>3)&3)*16 + (b&15), elem = k&7
__device__ __forceinline__ void scat(u16* buf, int nch, int b, int k, u16 v){
  buf[ (size_t)((((b>>4)*nch + (k>>5))*4 + ((k>>3)&3))*16 + (b&15))*8 + (k&7) ] = v;
}

// ---------------- weight prep (fragment-swizzled fp16) ----------------
__global__ __launch_bounds__(256) void prep_w1f(const float* __restrict__ Wih1,
    const float* __restrict__ Whh1, u16* __restrict__ Wf){
  int u = blockIdx.x*256 + threadIdx.x;          // exactly 655360 units
  int tile = u / 2560;
  int r = u - tile*2560;
  int kc = r >> 6, l = r & 63;
  int row = (tile>>6)*1024 + (tile&63)*16 + (l&15);
  int k0 = kc*32 + ((l>>4)<<3);
  half8 hv;
  #pragma unroll
  for (int e=0;e<8;e++){
    int k = k0+e;
    float w = 0.f;
    if (k < 171)       w = Wih1[(size_t)row*171 + k];
    else if (k < 1195) w = Whh1[(size_t)row*1024 + (k-171)];
    hv[e] = (_Float16)w;
  }
  *(half8*)&Wf[(size_t)(tile*40 + kc)*512 + (size_t)l*8] = hv;
}

__global__ __launch_bounds__(256) void prep_w23f(const float* __restrict__ Wih2,
    const float* __restrict__ Whh2, const float* __restrict__ Wih3,
    const float* __restrict__ Whh3, u16* __restrict__ W2f, u16* __restrict__ W3f){
  int u = blockIdx.x*256 + threadIdx.x;          // exactly 1048576 units
  int tile = u >> 12;
  int r = u & 4095;
  int kc = r >> 6, l = r & 63;
  int row = (tile>>6)*1024 + (tile&63)*16 + (l&15);
  int k0 = kc*32 + ((l>>4)<<3);
  half8 h2, h3;
  #pragma unroll
  for (int e=0;e<8;e++){
    int k = k0+e;
    size_t si = (size_t)row*1024 + (k & 1023);
    h2[e] = (_Float16)((k < 1024) ? Wih2[si] : Whh2[si]);
    h3[e] = (_Float16)((k < 1024) ? Wih3[si] : Whh3[si]);
  }
  size_t base = (size_t)(tile*64 + kc)*512 + (size_t)l*8;
  *(half8*)&W2f[base] = h2;
  *(half8*)&W3f[base] = h3;
}

__global__ __launch_bounds__(256) void prep_wdecf(const float* __restrict__ Wdec,
    u16* __restrict__ Wdf){
  int u = blockIdx.x*256 + threadIdx.x;          // exactly 22528 units
  int tile = u / 2048;
  int r = u & 2047;
  int kc = r >> 6, l = r & 63;
  int row = tile*16 + (l&15);
  int k0 = kc*32 + ((l>>4)<<3);
  half8 hv;
  #pragma unroll
  for (int e=0;e<8;e++){
    int k = k0+e;
    hv[e] = (_Float16)((row < 171) ? Wdec[(size_t)row*1024 + k] : 0.f);
  }
  *(half8*)&Wdf[(size_t)(tile*32 + kc)*512 + (size_t)l*8] = hv;
}

// biases + activation-buffer init (+ step-0 frame) + c init + barrier counters
__global__ __launch_bounds__(256) void prep_misc(
    const float* __restrict__ rseq, const int* __restrict__ gnp,
    const float* __restrict__ bih1, const float* __restrict__ bhh1,
    const float* __restrict__ bih2, const float* __restrict__ bhh2,
    const float* __restrict__ bih3, const float* __restrict__ bhh3,
    const float* __restrict__ bdec,
    u16* __restrict__ Xb1f, u16* __restrict__ Hf, float* __restrict__ cbuf,
    float* __restrict__ b1, float* __restrict__ b2, float* __restrict__ b3,
    float* __restrict__ bd, int* __restrict__ bar)
{
  size_t idx = (size_t)blockIdx.x*256 + threadIdx.x;
  if (idx < 327680){                       // Xb1f: 2 parities x [8][40][512]
    int q = (int)(idx / 163840);
    int rem = (int)(idx % 163840);
    int btile = rem / 20480;
    int r2 = rem % 20480;
    int kc = r2 >> 9, r3 = r2 & 511;
    int l = r3 >> 3, e = r3 & 7;
    int b = btile*16 + (l&15);
    int k = kc*32 + ((l>>4)<<3) + e;
    float v = 0.f;
    if (q==0 && k < 171 && *gnp > 0) v = rseq[(size_t)b*TT*INF + k];
    Xb1f[idx] = f2h(v);
    return;
  }
  idx -= 327680;
  if (idx < 786432){ Hf[idx] = 0; return; }        // H0/H1/H2 x 2 parities
  idx -= 786432;
  if (idx < 393216){ cbuf[idx] = 0.f; return; }    // c0,c1,c2
  idx -= 393216;
  if (idx < 12288){
    int which = (int)(idx >> 12), j = (int)(idx & 4095);
    float v = (which==0)? (bih1[j]+bhh1[j]) : (which==1)? (bih2[j]+bhh2[j]) : (bih3[j]+bhh3[j]);
    ((which==0)?b1:(which==1)?b2:b3)[j] = v;
    return;
  }
  idx -= 12288;
  if (idx < 176){ bd[idx] = (idx < 171) ? bdec[idx] : 0.f; return; }
  idx -= 176;
  if (idx < 512) bar[idx] = 0;
}

// ---------------- grid barrier: relaxed far-atomics, ONE wb + ONE inv --------
// Monotonic counters (no resets). c1[i]=bar[i*32] (8 lines), c0=bar[288], gen=bar[320].
__device__ __forceinline__ void gridbar(int* __restrict__ bar, int bId, int bc, int* s_dead){
  __syncthreads();
  if (threadIdx.x == 0 && !(*s_dead)){
    __builtin_amdgcn_fence(__ATOMIC_RELEASE, "agent");           // one L2 writeback
    int* c1  = &bar[(bId & 7) * 32];
    int* c0  = &bar[288];
    int* gen = &bar[320];
    bool released = false;
    int o1 = __hip_atomic_fetch_add(c1, 1, __ATOMIC_RELAXED, __HIP_MEMORY_SCOPE_AGENT);
    if ((o1 & 31) == 31){
      int o0 = __hip_atomic_fetch_add(c0, 1, __ATOMIC_RELAXED, __HIP_MEMORY_SCOPE_AGENT);
      if ((o0 & 7) == 7){
        __hip_atomic_fetch_add(gen, 1, __ATOMIC_RELAXED, __HIP_MEMORY_SCOPE_AGENT);
        released = true;
      }
    }
    if (!released){
      long long t0 = clock64();
      while (__hip_atomic_fetch_add(gen, 0, __ATOMIC_RELAXED, __HIP_MEMORY_SCOPE_AGENT) < bc + 1){
        __builtin_amdgcn_s_sleep(8);
        if (clock64() - t0 > 30000000LL){ *s_dead = 1; break; }  // ~12ms escape
      }
    }
    __builtin_amdgcn_fence(__ATOMIC_ACQUIRE, "agent");           // one L2 invalidate
  }
  __syncthreads();
}

// ---------------- half-K GEMM for one wave (ping-pong, 1 group ahead) --------
template<int KHALF, int GS>
__device__ __forceinline__ void gemm_half(const u16* __restrict__ wp,
    const u16* __restrict__ a0p, const u16* __restrict__ a1p,
    floatx4& a0, floatx4& a1)
{
  constexpr int NG = KHALF/GS;
  half8 W[2][GS], X0[2][GS], X1[2][GS];
  #pragma unroll
  for (int i=0;i<GS;i++){
    W [0][i] = *(const half8*)(wp  + (size_t)i*512);
    X0[0][i] = *(const half8*)(a0p + (size_t)i*512);
    X1[0][i] = *(const half8*)(a1p + (size_t)i*512);
  }
  #pragma unroll
  for (int g8=0; g8<NG; g8++){
    const int cur = g8 & 1, nxt = cur ^ 1;
    if (g8+1 < NG){
      const size_t off = (size_t)(g8+1)*GS*512;
      #pragma unroll
      for (int i=0;i<GS;i++){
        W [nxt][i] = *(const half8*)(wp  + off + (size_t)i*512);
        X0[nxt][i] = *(const half8*)(a0p + off + (size_t)i*512);
        X1[nxt][i] = *(const half8*)(a1p + off + (size_t)i*512);
      }
    }
    #pragma unroll
    for (int i=0;i<GS;i++){
      a0 = __builtin_amdgcn_mfma_f32_16x16x32_f16(W[cur][i], X0[cur][i], a0, 0,0,0);
      a1 = __builtin_amdgcn_mfma_f32_16x16x32_f16(W[cur][i], X1[cur][i], a1, 0,0,0);
    }
  }
}

// ---------------- persistent kernel: 256 blocks x 512 threads ----------------
// Block = (js 16 units, nq 32 batch). 8 waves: wave w -> gate (w>>1), K-half (w&1).
__global__ void __launch_bounds__(512,2) acro_persist(
    const u16* __restrict__ W1f, const u16* __restrict__ W2f,
    const u16* __restrict__ W3f, const u16* __restrict__ Wdf,
    u16* __restrict__ Xb1f, u16* __restrict__ Hf, float* __restrict__ cbuf,
    const float* __restrict__ b1, const float* __restrict__ b2,
    const float* __restrict__ b3, const float* __restrict__ bd,
    const float* __restrict__ rseq, float* __restrict__ out,
    const int* __restrict__ cnp, const int* __restrict__ gnp, int* __restrict__ bar)
{
  __shared__ float gb[8][16][33];     // per-wave partials (+1 pad)
  __shared__ int s_dead;
  const int bId = (int)blockIdx.x;
  const int js = (bId & 7)*8 + ((bId >> 5) & 7);   // 4 nq-siblings share XCD class
  const int nq = (bId >> 3) & 3;
  const int tid = (int)threadIdx.x;
  const int w = tid >> 6, l = tid & 63;
  const int g = w >> 1, hf = w & 1;
  const int l15 = l & 15, lq = l >> 4;
  if (tid == 0) s_dead = 0;
  const int gnv = *gnp;
  int P = *cnp + gnv; if (P < 1) P = 1;
  int bc = 0;                          // barriers completed

  u16* H0[2] = { Hf,          Hf + HSZ   };
  u16* H1[2] = { Hf + 2*HSZ,  Hf + 3*HSZ };
  u16* H2[2] = { Hf + 4*HSZ,  Hf + 5*HSZ };
  const u16* W23[2] = { W2f, W3f };
  const float* b23[2] = { b2, b3 };

  __syncthreads();
  for (int t=0; t<TT; t++){
    const int pr = t & 1, nx = pr ^ 1;

    // ============ L1: x = [frame | h0(t-1)], NCH=40, halves of 20 (GS=4) =====
    {
      const u16* wp = W1f + ((size_t)(g*64 + js)*40 + (size_t)hf*20)*512 + (size_t)(l<<3);
      const u16* xb = Xb1f + (size_t)pr*XBSZ;
      const u16* a0p = xb + ((size_t)(nq*2    )*40 + (size_t)hf*20)*512 + (size_t)(l<<3);
      const u16* a1p = xb + ((size_t)(nq*2 + 1)*40 + (size_t)hf*20)*512 + (size_t)(l<<3);
      floatx4 a0{}, a1{};
      gemm_half<20,4>(wp, a0p, a1p, a0, a1);
      #pragma unroll
      for (int r=0;r<4;r++){
        gb[w][lq*4+r][l15]      = a0[r];
        gb[w][lq*4+r][16 + l15] = a1[r];
      }
      __syncthreads();
      {
        int uu = tid >> 5, bq = tid & 31;
        int j = js*16 + uu, bg = nq*32 + bq;
        float gi = gb[0][uu][bq] + gb[1][uu][bq] + b1[j];
        float gf = gb[2][uu][bq] + gb[3][uu][bq] + b1[1024 + j];
        float gg = gb[4][uu][bq] + gb[5][uu][bq] + b1[2048 + j];
        float go = gb[6][uu][bq] + gb[7][uu][bq] + b1[3072 + j];
        size_t ci = (size_t)j*128 + bg;
        float c = sigm(gf)*cbuf[ci] + sigm(gi)*tanh_(gg);
        cbuf[ci] = c;
        u16 hb = f2h(sigm(go)*tanh_(c));
        scat(H0[pr], 32, bg, j, hb);
        scat(Xb1f + (size_t)nx*XBSZ, 40, bg, 171 + j, hb);
      }
    }
    gridbar(bar, bId, bc, &s_dead); bc++;

    // ============ L2, L3: NCH=64 = [x(32) | h(32)], halves of 32 (GS=8) ======
    #pragma unroll 1
    for (int ly=0; ly<2; ly++){
      const u16* xa = (ly==0) ? H0[pr] : H1[pr];     // half 0 source
      const u16* xh = (ly==0) ? H1[nx] : H2[nx];     // half 1 source
      u16* hd      = (ly==0) ? H1[pr] : H2[pr];
      float* cb    = cbuf + (size_t)(ly+1)*131072;
      const float* bb = b23[ly];
      const u16* wp = W23[ly] + ((size_t)(g*64 + js)*64 + (size_t)hf*32)*512 + (size_t)(l<<3);
      const u16* src = hf ? xh : xa;
      const u16* a0p = src + (size_t)(nq*2    )*32*512 + (size_t)(l<<3);
      const u16* a1p = src + (size_t)(nq*2 + 1)*32*512 + (size_t)(l<<3);
      floatx4 a0{}, a1{};
      gemm_half<32,8>(wp, a0p, a1p, a0, a1);
      #pragma unroll
      for (int r=0;r<4;r++){
        gb[w][lq*4+r][l15]      = a0[r];
        gb[w][lq*4+r][16 + l15] = a1[r];
      }
      __syncthreads();
      {
        int uu = tid >> 5, bq = tid & 31;
        int j = js*16 + uu, bg = nq*32 + bq;
        float gi = gb[0][uu][bq] + gb[1][uu][bq] + bb[j];
        float gf = gb[2][uu][bq] + gb[3][uu][bq] + bb[1024 + j];
        float gg = gb[4][uu][bq] + gb[5][uu][bq] + bb[2048 + j];
        float go = gb[6][uu][bq] + gb[7][uu][bq] + bb[3072 + j];
        size_t ci = (size_t)j*128 + bg;
        float c = sigm(gf)*cb[ci] + sigm(gi)*tanh_(gg);
        cb[ci] = c;
        u16 hb = f2h(sigm(go)*tanh_(c));
        scat(hd, 32, bg, j, hb);
      }
      gridbar(bar, bId, bc, &s_dead); bc++;
    }

    // ============ dec: blocks 0..43 = (tile, dq); waves split K 8 ways =======
    if (bId < 44){
      const int tile = bId >> 2, dq = bId & 3;
      const u16* wp = Wdf + (size_t)(tile*32 + w*4)*512 + (size_t)(l<<3);
      const u16* x0 = H2[pr] + (size_t)((dq*2    )*32 + w*4)*512 + (size_t)(l<<3);
      const u16* x1 = H2[pr] + (size_t)((dq*2 + 1)*32 + w*4)*512 + (size_t)(l<<3);
      floatx4 d0{}, d1{};
      #pragma unroll
      for (int i=0;i<4;i++){
        half8 wv = *(const half8*)(wp + (size_t)i*512);
        half8 a0 = *(const half8*)(x0 + (size_t)i*512);
        half8 a1 = *(const half8*)(x1 + (size_t)i*512);
        d0 = __builtin_amdgcn_mfma_f32_16x16x32_f16(wv, a0, d0, 0,0,0);
        d1 = __builtin_amdgcn_mfma_f32_16x16x32_f16(wv, a1, d1, 0,0,0);
      }
      #pragma unroll
      for (int r=0;r<4;r++){
        gb[w][lq*4+r][l15]      = d0[r];
        gb[w][lq*4+r][16 + l15] = d1[r];
      }
      __syncthreads();
      const int nf = (((t+1) % P) < gnv) ? 1 : 0;
      {
        int uu = tid >> 5, bq = tid & 31;
        int o = tile*16 + uu, b = dq*32 + bq;
        if (o < 171){
          float v = bd[o];
          #pragma unroll
          for (int i=0;i<8;i++) v += gb[i][uu][bq];
          out[((size_t)b*TT + t)*INF + o] = v;
          if (t+1 < TT){
            float src = nf ? rseq[((size_t)b*TT + (t+1))*INF + o] : v;
            scat(Xb1f + (size_t)nx*XBSZ, 40, b, o, f2h(src));
          }
        }
      }
    }
    gridbar(bar, bId, bc, &s_dead); bc++;
  }
}

// ---------------- host ----------------
extern "C" void kernel_launch(void* const* d_in, const int* in_sizes, int n_in,
                              void* d_out, int out_size, void* d_ws, size_t ws_size,
                              hipStream_t stream)
{
  const float* rseq = (const float*)d_in[0];
  const float* Wih1 = (const float*)d_in[1];
  const float* Whh1 = (const float*)d_in[2];
  const float* bih1 = (const float*)d_in[3];
  const float* bhh1 = (const float*)d_in[4];
  const float* Wih2 = (const float*)d_in[5];
  const float* Whh2 = (const float*)d_in[6];
  const float* bih2 = (const float*)d_in[7];
  const float* bhh2 = (const float*)d_in[8];
  const float* Wih3 = (const float*)d_in[9];
  const float* Whh3 = (const float*)d_in[10];
  const float* bih3 = (const float*)d_in[11];
  const float* bhh3 = (const float*)d_in[12];
  const float* Wdec = (const float*)d_in[13];
  const float* bdec = (const float*)d_in[14];
  const int* cn = (const int*)d_in[15];
  const int* gn = (const int*)d_in[16];
  float* out = (float*)d_out;

  char* p = (char*)d_ws;
  auto take = [&](size_t n){ void* r = (void*)p; p += (n + 255) & ~(size_t)255; return r; };
  u16* W1f  = (u16*)take(5242880UL*2);      // 256*40*512
  u16* W2f  = (u16*)take(8388608UL*2);      // 256*64*512
  u16* W3f  = (u16*)take(8388608UL*2);
  u16* Wdf  = (u16*)take(180224UL*2);       // 11*32*512
  u16* Xb1f = (u16*)take(327680UL*2);       // 2 parities x [8][40][512]
  u16* Hf   = (u16*)take(786432UL*2);       // 6 x [8][32][512]
  float* cbuf = (float*)take(393216UL*4);   // c0,c1,c2 [1024][128]
  float* b1 = (float*)take(4096*4);
  float* b2 = (float*)take(4096*4);
  float* b3 = (float*)take(4096*4);
  float* bd = (float*)take(176*4);
  int* bar  = (int*)take(512*4);
  if ((size_t)(p - (char*)d_ws) > ws_size) return;

  prep_w1f  <<<2560,256,0,stream>>>(Wih1, Whh1, W1f);
  prep_w23f <<<4096,256,0,stream>>>(Wih2, Whh2, Wih3, Whh3, W2f, W3f);
  prep_wdecf<<<88,  256,0,stream>>>(Wdec, Wdf);
  prep_misc <<<5939,256,0,stream>>>(rseq, gn, bih1,bhh1,bih2,bhh2,bih3,bhh3,bdec,
                                    Xb1f, Hf, cbuf, b1,b2,b3,bd, bar);

  acro_persist<<<256,512,0,stream>>>(W1f, W2f, W3f, Wdf, Xb1f, Hf, cbuf,
                                     b1, b2, b3, bd, rseq, out, cn, gn, bar);
}